// Round 6
// baseline (12908.594 us; speedup 1.0000x reference)
//
#include <hip/hip_runtime.h>
#include <cmath>

namespace {

constexpr int Dm  = 512;
constexpr int Bn  = 32;
constexpr int Lq  = 16;
constexpr int V1  = 8193;
constexpr int DFF = 2048;
constexpr int NL  = 2;
constexpr int NB  = 256;    // 32 groups x 8 blocks
constexpr int NT  = 1024;   // 16 waves/block
constexpr int GSTRIDE = 40960;  // floats per group workspace

struct Args {
  const int*   meanings;
  const float* emb_table;
  const float* v2e_w;
  const float* e2v_w;  const float* e2v_b;
  const float* sa_qkv_w; const float* sa_qkv_b;
  const float* sa_out_w; const float* sa_out_b;
  const float* ca_qkv_w; const float* ca_qkv_b;
  const float* ca_out_w; const float* ca_out_b;
  const float* ffn_w1; const float* ffn_b1;
  const float* ffn_w2; const float* ffn_b2;
  const float* ln1_g; const float* ln1_b;
  const float* ln2_g; const float* ln2_b;
  const float* ln3_g; const float* ln3_b;
  float* outToks;   // [16,32]
  float* outLogits; // [16,32,8193]
  unsigned* barSlots; // [32][16] u32
  float* gws;         // group workspaces
};

struct Frag { float v[8]; };

__device__ __forceinline__ float wred(float v) {
#pragma unroll
  for (int off = 32; off; off >>= 1) v += __shfl_down(v, off, 64);
  return v;
}
__device__ __forceinline__ float bfly(float v) {
#pragma unroll
  for (int m = 1; m < 64; m <<= 1) v += __shfl_xor(v, m, 64);
  return v;
}

__device__ __forceinline__ Frag fload(const float* __restrict__ p, int lane) {
  float4 a = *(const float4*)(p + lane * 4);
  float4 b = *(const float4*)(p + 256 + lane * 4);
  Frag f;
  f.v[0]=a.x; f.v[1]=a.y; f.v[2]=a.z; f.v[3]=a.w;
  f.v[4]=b.x; f.v[5]=b.y; f.v[6]=b.z; f.v[7]=b.w;
  return f;
}
__device__ __forceinline__ void fstore(float* __restrict__ p, const Frag& f, int lane) {
  *(float4*)(p + lane * 4)       = make_float4(f.v[0], f.v[1], f.v[2], f.v[3]);
  *(float4*)(p + 256 + lane * 4) = make_float4(f.v[4], f.v[5], f.v[6], f.v[7]);
}
// dot(weight_row[512], frag); result valid on lane 0
__device__ __forceinline__ float fdot(const float* __restrict__ wr, const Frag& x, int lane) {
  float4 a = *(const float4*)(wr + lane * 4);
  float4 b = *(const float4*)(wr + 256 + lane * 4);
  float acc = a.x*x.v[0] + a.y*x.v[1] + a.z*x.v[2] + a.w*x.v[3]
            + b.x*x.v[4] + b.y*x.v[5] + b.z*x.v[6] + b.w*x.v[7];
  return wred(acc);
}
// in-register LayerNorm of a full 512-row held as lane fragments (all lanes get result)
__device__ __forceinline__ Frag fln(const Frag& r, const float* __restrict__ gp,
                                    const float* __restrict__ bp, int lane) {
  float s = 0.f, q = 0.f;
#pragma unroll
  for (int k = 0; k < 8; ++k) { s += r.v[k]; q += r.v[k] * r.v[k]; }
  s = bfly(s); q = bfly(q);
  float mean = s * (1.f / Dm);
  float var  = q * (1.f / Dm) - mean * mean;
  float inv  = 1.f / sqrtf(var + 1e-5f);
  Frag g = fload(gp, lane), b = fload(bp, lane), o;
#pragma unroll
  for (int k = 0; k < 8; ++k) o.v[k] = (r.v[k] - mean) * inv * g.v[k] + b.v[k];
  return o;
}
__device__ __forceinline__ Frag fadd(const Frag& a, const Frag& b) {
  Frag o;
#pragma unroll
  for (int k = 0; k < 8; ++k) o.v[k] = a.v[k] + b.v[k];
  return o;
}

__device__ __forceinline__ float pe_val(int t, int i) {
  int j2 = t & ~1;
  float div = expf((float)j2 * (-9.210340371976184f / 512.0f));
  float ang = (float)i * div;
  return (t & 1) ? cosf(ang) : sinf(ang);
}

// --- 8-block group barrier: one 64B slot line, all-to-all poll, ~2us ---
__device__ __forceinline__ void gbar8(unsigned* __restrict__ slots, int idx,
                                      unsigned e, int tid, int lane) {
  __syncthreads();  // block work done (vmcnt drained by barrier semantics)
  if (tid == 0)
    __hip_atomic_store(&slots[idx], e, __ATOMIC_RELEASE, __HIP_MEMORY_SCOPE_AGENT);
  for (;;) {
    unsigned v = (lane < 8)
        ? __hip_atomic_load(&slots[lane], __ATOMIC_RELAXED, __HIP_MEMORY_SCOPE_AGENT)
        : 0xFFFFFFFFu;
    if (__all((lane >= 8) || (v >= e))) break;
    __builtin_amdgcn_s_sleep(4);
  }
  __threadfence();  // acquire: see other blocks' writes
}

__global__ __launch_bounds__(NT, 4) void mega(Args a) {
  const int tid  = threadIdx.x;
  const int bid  = blockIdx.x;
  const int lane = tid & 63;
  const int wave = tid >> 6;          // 0..15
  const int grp  = bid & 31;          // batch element owned by this group
  const int idx  = bid >> 5;          // 0..7 within group
  const int gwave = idx * 16 + wave;  // 0..127
  const int b    = grp;
  unsigned ep = 0;
  __shared__ float sAout[Dm];
  __shared__ float sS[Lq];
  __shared__ int   sTok;

  unsigned* slots = a.barSlots + grp * 16;
  float* W = a.gws + (size_t)grp * GSTRIDE;
  float* q     = W;            // 512
  float* x     = W + 512;      // 512  (embedding output)
  float* xln   = W + 1024;     // 512  (layer-1 residual input = LN3 of layer 0)
  float* x2    = W + 1536;     // 512  (LN2 output of current layer)
  float* tmpv  = W + 2048;     // 512  (attn out-proj)
  float* tmpv2 = W + 2560;     // 512  (FFN2 out)
  float* catmp = W + 3072;     // 1024
  float* caC   = W + 4096;     // 1024 (per-layer cross-attn constant)
  float* h1    = W + 5120;     // 2048
  float* partV = W + 7168;     // 128
  int*   partI = (int*)(W + 7296); // 128
  float* kc    = W + 7424;     // 2*16*512
  float* vc    = W + 23808;    // 2*16*512

  // src fragment (cross-attn memory for this b) — computed redundantly per wave
  Frag srcf;
#pragma unroll
  for (int k = 0; k < 8; ++k) srcf.v[k] = 0.f;
#pragma unroll
  for (int ty = 0; ty < 8; ++ty) {
    int id = a.meanings[b * 8 + ty] + ty * 32;
    Frag e = fload(a.emb_table + (size_t)id * Dm, lane);
#pragma unroll
    for (int k = 0; k < 8; ++k) srcf.v[k] += e.v[k];
  }

  // ---- setup0: catmp = Wv*src + bv (both layers); block0 writes step-0 x ----
  for (int u = gwave; u < NL * Dm; u += 128) {
    int l = u >> 9, n = u & 511;
    float acc = fdot(a.ca_qkv_w + ((size_t)l * 3 * Dm + 2 * Dm + n) * Dm, srcf, lane);
    if (lane == 0) catmp[l * Dm + n] = acc + a.ca_qkv_b[l * 3 * Dm + 2 * Dm + n];
  }
  if (idx == 0 && tid < Dm)
    x[tid] = a.v2e_w[(size_t)(V1 - 1) * Dm + tid] + pe_val(tid, 0);
  gbar8(slots, idx, ++ep, tid, lane);

  // ---- setup1: caC = Wout*catmp + bout (softmax over single key == 1) ----
  for (int u = gwave; u < NL * Dm; u += 128) {
    int l = u >> 9, n = u & 511;
    Frag cf = fload(catmp + l * Dm, lane);
    float acc = fdot(a.ca_out_w + ((size_t)l * Dm + n) * Dm, cf, lane);
    if (lane == 0) caC[l * Dm + n] = acc + a.ca_out_b[l * Dm + n];
  }
  gbar8(slots, idx, ++ep, tid, lane);

  for (int i = 0; i < Lq; ++i) {
    for (int l = 0; l < NL; ++l) {
      float* kslot = kc + (l * Lq + i) * Dm;
      float* vslot = vc + (l * Lq + i) * Dm;

      // --- S1: QKV (1536 rows / 128 waves); layer1 fuses LN3 of layer0 ---
      {
        Frag xf;
        if (l == 0) {
          xf = fload(x, lane);
        } else {
          Frag r = fadd(fload(x2, lane), fload(tmpv2, lane));
          xf = fln(r, a.ln3_g + 0 * Dm, a.ln3_b + 0 * Dm, lane);
          if (gwave == 0) fstore(xln, xf, lane);  // layer-1 residual input
        }
        const float* Wq = a.sa_qkv_w + (size_t)l * 3 * Dm * Dm;
        const float* bq = a.sa_qkv_b + l * 3 * Dm;
        for (int n = gwave; n < 3 * Dm; n += 128) {
          float acc = fdot(Wq + (size_t)n * Dm, xf, lane);
          if (lane == 0) {
            float r = acc + bq[n];
            if (n < Dm)           q[n] = r;
            else if (n < 2 * Dm)  kslot[n - Dm] = r;
            else                  vslot[n - 2 * Dm] = r;
          }
        }
      }
      gbar8(slots, idx, ++ep, tid, lane);

      // --- S2: attn (redundant per block) + out-projection ---
      {
        if (wave <= i) {
          Frag qf = fload(q, lane);
          float acc = fdot(kc + (l * Lq + wave) * Dm, qf, lane);
          if (lane == 0) sS[wave] = acc * 0.04419417382415922f;  // 1/sqrt(512)
        }
        __syncthreads();
        if (tid == 0) {
          float m = -1e30f;
          for (int j = 0; j <= i; ++j) m = fmaxf(m, sS[j]);
          float s = 0.f;
          for (int j = 0; j <= i; ++j) { float e = expf(sS[j] - m); sS[j] = e; s += e; }
          float inv = 1.f / s;
          for (int j = 0; j <= i; ++j) sS[j] *= inv;
        }
        __syncthreads();
        if (tid < Dm) {
          float acc = 0.f;
          for (int j = 0; j <= i; ++j) acc += sS[j] * vc[(l * Lq + j) * Dm + tid];
          sAout[tid] = acc;
        }
        __syncthreads();
        Frag af = fload(sAout, lane);
#pragma unroll
        for (int r = 0; r < 4; ++r) {
          int n = gwave + 128 * r;
          float acc = fdot(a.sa_out_w + ((size_t)l * Dm + n) * Dm, af, lane);
          if (lane == 0) tmpv[n] = acc + a.sa_out_b[l * Dm + n];
        }
      }
      gbar8(slots, idx, ++ep, tid, lane);

      // --- S3: in-register LN1+ca+LN2, then FFN1 (2048 rows / 128 waves) ---
      {
        Frag xin = (l == 0) ? fload(x, lane) : fload(xln, lane);
        Frag r = fadd(xin, fload(tmpv, lane));
        Frag l1 = fln(r, a.ln1_g + l * Dm, a.ln1_b + l * Dm, lane);
        Frag r2 = fadd(l1, fload(caC + l * Dm, lane));
        Frag xm = fln(r2, a.ln2_g + l * Dm, a.ln2_b + l * Dm, lane);
        if (gwave == 0) fstore(x2, xm, lane);
        const float* W1 = a.ffn_w1 + (size_t)l * DFF * Dm;
        const float* b1 = a.ffn_b1 + l * DFF;
        for (int n = gwave; n < DFF; n += 128) {
          float acc = fdot(W1 + (size_t)n * Dm, xm, lane);
          if (lane == 0) h1[n] = fmaxf(acc + b1[n], 0.f);
        }
      }
      gbar8(slots, idx, ++ep, tid, lane);

      // --- S4: FFN2 (512 rows / 128 waves, K=2048) ---
      {
        float4 h8[8];
#pragma unroll
        for (int k = 0; k < 8; ++k) h8[k] = *(const float4*)(h1 + k * 256 + lane * 4);
        const float* W2 = a.ffn_w2 + (size_t)l * Dm * DFF;
        const float* b2 = a.ffn_b2 + l * Dm;
#pragma unroll
        for (int r = 0; r < 4; ++r) {
          int n = gwave + 128 * r;
          const float* wr = W2 + (size_t)n * DFF;
          float acc = 0.f;
#pragma unroll
          for (int k = 0; k < 8; ++k) {
            float4 w4 = *(const float4*)(wr + k * 256 + lane * 4);
            acc += w4.x * h8[k].x + w4.y * h8[k].y + w4.z * h8[k].z + w4.w * h8[k].w;
          }
          acc = wred(acc);
          if (lane == 0) tmpv2[n] = acc + b2[n];
        }
      }
      gbar8(slots, idx, ++ep, tid, lane);
    }

    // --- logits (8193 rows / 128 waves) with fused LN3(layer1) + running argmax ---
    {
      Frag r = fadd(fload(x2, lane), fload(tmpv2, lane));
      Frag xf = fln(r, a.ln3_g + 1 * Dm, a.ln3_b + 1 * Dm, lane);
      float* lg = a.outLogits + (size_t)(i * Bn + b) * V1;
      float pm = -1e30f; int pidx = 0;
      for (int n = gwave; n < V1; n += 128) {
        float acc = fdot(a.e2v_w + (size_t)n * Dm, xf, lane);
        if (lane == 0) {
          float val = acc + a.e2v_b[n];
          lg[n] = val;
          if (val > pm) { pm = val; pidx = n; }  // n ascending: first-max kept
        }
      }
      if (lane == 0) { partV[gwave] = pm; partI[gwave] = pidx; }
    }
    gbar8(slots, idx, ++ep, tid, lane);

    // --- argmax combine (block idx0 of group) + next-step embedding ---
    if (idx == 0) {
      if (wave == 0) {
        float v0 = partV[lane];       int i0 = partI[lane];
        float v1 = partV[64 + lane];  int i1 = partI[64 + lane];
        if (v1 > v0 || (v1 == v0 && i1 < i0)) { v0 = v1; i0 = i1; }
#pragma unroll
        for (int m = 1; m < 64; m <<= 1) {
          float ov = __shfl_xor(v0, m, 64); int oi = __shfl_xor(i0, m, 64);
          if (ov > v0 || (ov == v0 && oi < i0)) { v0 = ov; i0 = oi; }
        }
        if (lane == 0) { a.outToks[i * Bn + b] = (float)i0; sTok = i0; }
      }
      __syncthreads();
      if (i + 1 < Lq && tid < Dm) {
        int tok = sTok;
        x[tid] = a.v2e_w[(size_t)tok * Dm + tid] + pe_val(tid, i + 1);
      }
    }
    gbar8(slots, idx, ++ep, tid, lane);
  }
}

}  // namespace

extern "C" void kernel_launch(void* const* d_in, const int* in_sizes, int n_in,
                              void* d_out, int out_size, void* d_ws, size_t ws_size,
                              hipStream_t stream) {
  (void)in_sizes; (void)n_in; (void)out_size; (void)ws_size;

  float* out = (float*)d_out;
  char* wsb = (char*)d_ws;

  Args a;
  a.meanings  = (const int*)d_in[0];
  a.emb_table = (const float*)d_in[1];
  a.v2e_w     = (const float*)d_in[2];
  a.e2v_w     = (const float*)d_in[3];
  a.e2v_b     = (const float*)d_in[4];
  a.sa_qkv_w  = (const float*)d_in[5];
  a.sa_qkv_b  = (const float*)d_in[6];
  a.sa_out_w  = (const float*)d_in[7];
  a.sa_out_b  = (const float*)d_in[8];
  a.ca_qkv_w  = (const float*)d_in[9];
  a.ca_qkv_b  = (const float*)d_in[10];
  a.ca_out_w  = (const float*)d_in[11];
  a.ca_out_b  = (const float*)d_in[12];
  a.ffn_w1    = (const float*)d_in[13];
  a.ffn_b1    = (const float*)d_in[14];
  a.ffn_w2    = (const float*)d_in[15];
  a.ffn_b2    = (const float*)d_in[16];
  a.ln1_g     = (const float*)d_in[17];
  a.ln1_b     = (const float*)d_in[18];
  a.ln2_g     = (const float*)d_in[19];
  a.ln2_b     = (const float*)d_in[20];
  a.ln3_g     = (const float*)d_in[21];
  a.ln3_b     = (const float*)d_in[22];
  a.outToks   = out;
  a.outLogits = out + Lq * Bn;

  a.barSlots = (unsigned*)wsb;              // 32 groups x 16 u32 = 2KB
  hipMemsetAsync(wsb, 0, 4096, stream);
  a.gws = (float*)(wsb + 4096);             // 32 x GSTRIDE floats (~5.25 MB)

  void* kp[] = { (void*)&a };
  hipLaunchCooperativeKernel((const void*)mega, dim3(NB), dim3(NT), kp, 0, stream);
}

// Round 7
// 7856.499 us; speedup vs baseline: 1.6430x; 1.6430x over previous
//
#include <hip/hip_runtime.h>
#include <cmath>

namespace {

constexpr int Dm  = 512;
constexpr int Bn  = 32;
constexpr int Lq  = 16;
constexpr int V1  = 8193;
constexpr int DFF = 2048;
constexpr int NL  = 2;
constexpr int NB  = 256;    // 1 block/CU
constexpr int NT  = 1024;   // 16 waves/block
constexpr int NGW = NB * 16;  // 4096 waves

struct Args {
  const int*   meanings;
  const float* emb_table;
  const float* v2e_w;
  const float* e2v_w;  const float* e2v_b;
  const float* sa_qkv_w; const float* sa_qkv_b;
  const float* sa_out_w; const float* sa_out_b;
  const float* ca_qkv_w; const float* ca_qkv_b;
  const float* ca_out_w; const float* ca_out_b;
  const float* ffn_w1; const float* ffn_b1;
  const float* ffn_w2; const float* ffn_b2;
  const float* ln1_g; const float* ln1_b;
  const float* ln2_g; const float* ln2_b;
  const float* ln3_g; const float* ln3_b;
  float* outToks;   // [16,32]
  float* outLogits; // [16,32,8193]
  unsigned* slots;  // [256]
  float* q; float* x; float* xln; float* x2; float* tmpv; float* tmpv2;
  float* catmp; float* caC; float* h1; float* kc; float* vc; float* partPack;
};

struct Frag { float v[8]; };

// ---- coherent (agent-scope, L3-backed) activation I/O: no fences needed ----
__device__ __forceinline__ void cst(float* p, float v) {
  __hip_atomic_store((unsigned*)p, __float_as_uint(v),
                     __ATOMIC_RELAXED, __HIP_MEMORY_SCOPE_AGENT);
}
__device__ __forceinline__ void cst2(float* p, float a, float b) {
  unsigned long long u = ((unsigned long long)__float_as_uint(b) << 32)
                       | __float_as_uint(a);
  __hip_atomic_store((unsigned long long*)p, u,
                     __ATOMIC_RELAXED, __HIP_MEMORY_SCOPE_AGENT);
}
__device__ __forceinline__ float2 cld2(const float* p) {
  unsigned long long u = __hip_atomic_load((const unsigned long long*)p,
                     __ATOMIC_RELAXED, __HIP_MEMORY_SCOPE_AGENT);
  return make_float2(__uint_as_float((unsigned)u),
                     __uint_as_float((unsigned)(u >> 32)));
}
__device__ __forceinline__ void cstp(float* p, float v, int idx) {
  unsigned long long u = ((unsigned long long)(unsigned)idx << 32)
                       | __float_as_uint(v);
  __hip_atomic_store((unsigned long long*)p, u,
                     __ATOMIC_RELAXED, __HIP_MEMORY_SCOPE_AGENT);
}

__device__ __forceinline__ float wred(float v) {
#pragma unroll
  for (int off = 32; off; off >>= 1) v += __shfl_down(v, off, 64);
  return v;
}
__device__ __forceinline__ float bfly(float v) {
#pragma unroll
  for (int m = 1; m < 64; m <<= 1) v += __shfl_xor(v, m, 64);
  return v;
}

// plain (cached) fragment load — weights/LDS/read-only inputs
__device__ __forceinline__ Frag fload(const float* __restrict__ p, int lane) {
  float4 a = *(const float4*)(p + lane * 4);
  float4 b = *(const float4*)(p + 256 + lane * 4);
  Frag f;
  f.v[0]=a.x; f.v[1]=a.y; f.v[2]=a.z; f.v[3]=a.w;
  f.v[4]=b.x; f.v[5]=b.y; f.v[6]=b.z; f.v[7]=b.w;
  return f;
}
// coherent fragment load/store — activations
__device__ __forceinline__ Frag cfload(const float* p, int lane) {
  float2 a0 = cld2(p + lane * 4),       a1 = cld2(p + lane * 4 + 2);
  float2 b0 = cld2(p + 256 + lane * 4), b1 = cld2(p + 256 + lane * 4 + 2);
  Frag f;
  f.v[0]=a0.x; f.v[1]=a0.y; f.v[2]=a1.x; f.v[3]=a1.y;
  f.v[4]=b0.x; f.v[5]=b0.y; f.v[6]=b1.x; f.v[7]=b1.y;
  return f;
}
__device__ __forceinline__ void cfstore(float* p, const Frag& f, int lane) {
  cst2(p + lane * 4,       f.v[0], f.v[1]);
  cst2(p + lane * 4 + 2,   f.v[2], f.v[3]);
  cst2(p + 256 + lane * 4,     f.v[4], f.v[5]);
  cst2(p + 256 + lane * 4 + 2, f.v[6], f.v[7]);
}
// dot(weight_row[512] plain-cached, frag); valid on lane 0
__device__ __forceinline__ float fdot(const float* __restrict__ wr, const Frag& x, int lane) {
  float4 a = *(const float4*)(wr + lane * 4);
  float4 b = *(const float4*)(wr + 256 + lane * 4);
  float acc = a.x*x.v[0] + a.y*x.v[1] + a.z*x.v[2] + a.w*x.v[3]
            + b.x*x.v[4] + b.y*x.v[5] + b.z*x.v[6] + b.w*x.v[7];
  return wred(acc);
}
// dot with coherent row load — activation rows (k-cache)
__device__ __forceinline__ float cfdot(const float* p, const Frag& x, int lane) {
  float2 a0 = cld2(p + lane * 4),       a1 = cld2(p + lane * 4 + 2);
  float2 b0 = cld2(p + 256 + lane * 4), b1 = cld2(p + 256 + lane * 4 + 2);
  float acc = a0.x*x.v[0] + a0.y*x.v[1] + a1.x*x.v[2] + a1.y*x.v[3]
            + b0.x*x.v[4] + b0.y*x.v[5] + b1.x*x.v[6] + b1.y*x.v[7];
  return wred(acc);
}
// in-register LayerNorm of a 512-row spread across the wave (all lanes get result)
__device__ __forceinline__ Frag fln(const Frag& r, const float* __restrict__ gp,
                                    const float* __restrict__ bp, int lane) {
  float s = 0.f, q = 0.f;
#pragma unroll
  for (int k = 0; k < 8; ++k) { s += r.v[k]; q += r.v[k] * r.v[k]; }
  s = bfly(s); q = bfly(q);
  float mean = s * (1.f / Dm);
  float var  = q * (1.f / Dm) - mean * mean;
  float inv  = 1.f / sqrtf(var + 1e-5f);
  Frag g = fload(gp, lane), b = fload(bp, lane), o;
#pragma unroll
  for (int k = 0; k < 8; ++k) o.v[k] = (r.v[k] - mean) * inv * g.v[k] + b.v[k];
  return o;
}
__device__ __forceinline__ Frag fadd(const Frag& a, const Frag& b) {
  Frag o;
#pragma unroll
  for (int k = 0; k < 8; ++k) o.v[k] = a.v[k] + b.v[k];
  return o;
}

__device__ __forceinline__ float pe_val(int t, int i) {
  int j2 = t & ~1;
  float div = expf((float)j2 * (-9.210340371976184f / 512.0f));
  float ang = (float)i * div;
  return (t & 1) ? cosf(ang) : sinf(ang);
}

// ---- fence-free grid barrier: __syncthreads drains vmcnt (coherent stores at
// L3), arrival flag relaxed-agent, wave0 polls all 256 slots single-hop ----
__device__ __forceinline__ void gbar(unsigned* slots, unsigned e,
                                     int bid, int tid, int lane, int wave) {
  __syncthreads();
  if (tid == 0)
    __hip_atomic_store(&slots[bid], e, __ATOMIC_RELAXED, __HIP_MEMORY_SCOPE_AGENT);
  if (wave == 0) {
    for (;;) {
      bool ok = true;
#pragma unroll
      for (int k = 0; k < 4; ++k) {
        unsigned v = __hip_atomic_load(&slots[lane * 4 + k],
                        __ATOMIC_RELAXED, __HIP_MEMORY_SCOPE_AGENT);
        ok &= (v >= e);
      }
      if (__all(ok)) break;
      __builtin_amdgcn_s_sleep(2);
    }
  }
  __syncthreads();
}

__global__ __launch_bounds__(NT, 4) void mega(Args a) {
  const int tid  = threadIdx.x;
  const int bid  = blockIdx.x;
  const int lane = tid & 63;
  const int wave = tid >> 6;          // 0..15
  const int gw   = bid * 16 + wave;   // 0..4095
  const int g4   = gw & 3;            // b-group (8 b's) for frag8 stages
  unsigned ep = 0;

  __shared__ float sAout[Dm];
  __shared__ float sS[Lq];
  __shared__ float sv[NT];
  __shared__ int   si[NT];
  __shared__ int   sTok;

  // ---- setup0: catmp = Wv*src + bv (src recomputed in-register); step-0 embed ----
  {
    Frag srcf[8];
#pragma unroll
    for (int j = 0; j < 8; ++j) {
      int b = g4 * 8 + j;
#pragma unroll
      for (int k = 0; k < 8; ++k) srcf[j].v[k] = 0.f;
#pragma unroll
      for (int ty = 0; ty < 8; ++ty) {
        int id = a.meanings[b * 8 + ty] + ty * 32;
        Frag e = fload(a.emb_table + (size_t)id * Dm, lane);
#pragma unroll
        for (int k = 0; k < 8; ++k) srcf[j].v[k] += e.v[k];
      }
    }
    int r = gw >> 2, n = r & 511, l = r >> 9;   // 4096 units exactly
    const float* wr = a.ca_qkv_w + ((size_t)l * 3 * Dm + 2 * Dm + n) * Dm;
    float bn = a.ca_qkv_b[l * 3 * Dm + 2 * Dm + n];
#pragma unroll
    for (int j = 0; j < 8; ++j) {
      float acc = fdot(wr, srcf[j], lane);
      if (lane == 0) cst(a.catmp + ((size_t)(l * Bn + g4 * 8 + j)) * Dm + n, acc + bn);
    }
    if (bid < Bn && tid < 256) {
      int b = bid, t2 = tid * 2;
      float e0 = a.v2e_w[(size_t)(V1 - 1) * Dm + t2]     + pe_val(t2, 0);
      float e1 = a.v2e_w[(size_t)(V1 - 1) * Dm + t2 + 1] + pe_val(t2 + 1, 0);
      cst2(a.x + b * Dm + t2, e0, e1);
    }
  }
  gbar(a.slots, ++ep, bid, tid, lane, wave);

  // ---- setup1: caC = Wout*catmp + bout (cross-attn const; softmax over 1 key == 1) ----
  {
    int r = gw >> 2, n = r & 511, l = r >> 9;
    const float* wr = a.ca_out_w + ((size_t)l * Dm + n) * Dm;
    float bn = a.ca_out_b[l * Dm + n];
#pragma unroll
    for (int j = 0; j < 8; ++j) {
      Frag cf = cfload(a.catmp + ((size_t)(l * Bn + g4 * 8 + j)) * Dm, lane);
      float acc = fdot(wr, cf, lane);
      if (lane == 0) cst(a.caC + ((size_t)(l * Bn + g4 * 8 + j)) * Dm + n, acc + bn);
    }
  }
  gbar(a.slots, ++ep, bid, tid, lane, wave);

  for (int i = 0; i < Lq; ++i) {
    for (int l = 0; l < NL; ++l) {
      float* kcl = a.kc + (size_t)l * Lq * Bn * Dm;
      float* vcl = a.vc + (size_t)l * Lq * Bn * Dm;
      float* kslot = kcl + (size_t)i * Bn * Dm;
      float* vslot = vcl + (size_t)i * Bn * Dm;

      // --- S1: QKV (1536 rows x 8 b/wave); layer1 fuses LN3 of layer0 ---
      {
        Frag xf[8];
#pragma unroll
        for (int j = 0; j < 8; ++j) {
          int b = g4 * 8 + j;
          if (l == 0) {
            xf[j] = cfload(a.x + b * Dm, lane);
          } else {
            Frag r = fadd(cfload(a.x2 + b * Dm, lane), cfload(a.tmpv2 + b * Dm, lane));
            xf[j] = fln(r, a.ln3_g, a.ln3_b, lane);  // layer-0 LN3
          }
        }
        if (l == 1 && gw < 4) {
#pragma unroll
          for (int j = 0; j < 8; ++j) cfstore(a.xln + (g4 * 8 + j) * Dm, xf[j], lane);
        }
        const float* Wq = a.sa_qkv_w + (size_t)l * 3 * Dm * Dm;
        const float* bq = a.sa_qkv_b + l * 3 * Dm;
        for (int u = gw; u < 3 * Dm * 4; u += NGW) {
          int n = u >> 2;
          const float* wr = Wq + (size_t)n * Dm;
          float bn = bq[n];
#pragma unroll
          for (int j = 0; j < 8; ++j) {
            float acc = fdot(wr, xf[j], lane);
            if (lane == 0) {
              int b = g4 * 8 + j;
              float rr = acc + bn;
              if (n < Dm)           cst(a.q + b * Dm + n, rr);
              else if (n < 2 * Dm)  cst(kslot + b * Dm + (n - Dm), rr);
              else                  cst(vslot + b * Dm + (n - 2 * Dm), rr);
            }
          }
        }
      }
      gbar(a.slots, ++ep, bid, tid, lane, wave);

      // --- S2: attn core + out-projection (per-b block) ---
      if (bid < Bn) {
        const int b = bid;
        if (wave <= i) {
          Frag qf = cfload(a.q + b * Dm, lane);
          float acc = cfdot(kcl + ((size_t)wave * Bn + b) * Dm, qf, lane);
          if (lane == 0) sS[wave] = acc * 0.04419417382415922f;  // 1/sqrt(512)
        }
        __syncthreads();
        if (tid == 0) {
          float m = -1e30f;
          for (int j = 0; j <= i; ++j) m = fmaxf(m, sS[j]);
          float s = 0.f;
          for (int j = 0; j <= i; ++j) { float e = expf(sS[j] - m); sS[j] = e; s += e; }
          float inv = 1.f / s;
          for (int j = 0; j <= i; ++j) sS[j] *= inv;
        }
        __syncthreads();
        if (tid < 256) {
          int t2 = tid * 2;
          float a0 = 0.f, a1 = 0.f;
          for (int j = 0; j <= i; ++j) {
            float2 v2 = cld2(vcl + ((size_t)j * Bn + b) * Dm + t2);
            a0 += sS[j] * v2.x; a1 += sS[j] * v2.y;
          }
          sAout[t2] = a0; sAout[t2 + 1] = a1;
        }
        __syncthreads();
        Frag af = fload(sAout, lane);
        const float* Wo = a.sa_out_w + (size_t)l * Dm * Dm;
#pragma unroll
        for (int r = 0; r < 32; ++r) {
          int n = wave * 32 + r;
          float acc = fdot(Wo + (size_t)n * Dm, af, lane);
          if (lane == 0) cst(a.tmpv + b * Dm + n, acc + a.sa_out_b[l * Dm + n]);
        }
      }
      gbar(a.slots, ++ep, bid, tid, lane, wave);

      // --- S3: in-register LN1+ca+LN2, then FFN1 (2048 rows x 8 b/wave) ---
      {
        Frag xm[8];
#pragma unroll
        for (int j = 0; j < 8; ++j) {
          int b = g4 * 8 + j;
          Frag xin = (l == 0) ? cfload(a.x + b * Dm, lane) : cfload(a.xln + b * Dm, lane);
          Frag r  = fadd(xin, cfload(a.tmpv + b * Dm, lane));
          Frag l1 = fln(r, a.ln1_g + l * Dm, a.ln1_b + l * Dm, lane);
          Frag r2 = fadd(l1, cfload(a.caC + ((size_t)(l * Bn + b)) * Dm, lane));
          xm[j]   = fln(r2, a.ln2_g + l * Dm, a.ln2_b + l * Dm, lane);
        }
        if (gw < 4) {
#pragma unroll
          for (int j = 0; j < 8; ++j) cfstore(a.x2 + (g4 * 8 + j) * Dm, xm[j], lane);
        }
        const float* W1 = a.ffn_w1 + (size_t)l * DFF * Dm;
        const float* b1 = a.ffn_b1 + l * DFF;
        for (int u = gw; u < DFF * 4; u += NGW) {
          int n = u >> 2;
          const float* wr = W1 + (size_t)n * Dm;
          float bn = b1[n];
#pragma unroll
          for (int j = 0; j < 8; ++j) {
            float acc = fdot(wr, xm[j], lane);
            if (lane == 0) cst(a.h1 + (size_t)(g4 * 8 + j) * DFF + n, fmaxf(acc + bn, 0.f));
          }
        }
      }
      gbar(a.slots, ++ep, bid, tid, lane, wave);

      // --- S4: FFN2 (512 rows x 2 b/wave, K=2048) ---
      {
        const int g16 = gw & 15;
        const int b0 = g16 * 2;
        float4 ha[8], hb[8];
#pragma unroll
        for (int k = 0; k < 8; ++k) {
          float2 p0 = cld2(a.h1 + (size_t)b0 * DFF + k * 256 + lane * 4);
          float2 p1 = cld2(a.h1 + (size_t)b0 * DFF + k * 256 + lane * 4 + 2);
          ha[k] = make_float4(p0.x, p0.y, p1.x, p1.y);
          float2 q0 = cld2(a.h1 + (size_t)(b0 + 1) * DFF + k * 256 + lane * 4);
          float2 q1 = cld2(a.h1 + (size_t)(b0 + 1) * DFF + k * 256 + lane * 4 + 2);
          hb[k] = make_float4(q0.x, q0.y, q1.x, q1.y);
        }
        const float* W2 = a.ffn_w2 + (size_t)l * Dm * DFF;
        const float* b2 = a.ffn_b2 + l * Dm;
        for (int u = gw; u < Dm * 16; u += NGW) {
          int n = u >> 4;
          const float* wr = W2 + (size_t)n * DFF;
          float pa = 0.f, pb = 0.f;
#pragma unroll
          for (int k = 0; k < 8; ++k) {
            float4 w4 = *(const float4*)(wr + k * 256 + lane * 4);
            pa += w4.x * ha[k].x + w4.y * ha[k].y + w4.z * ha[k].z + w4.w * ha[k].w;
            pb += w4.x * hb[k].x + w4.y * hb[k].y + w4.z * hb[k].z + w4.w * hb[k].w;
          }
          pa = wred(pa); pb = wred(pb);
          if (lane == 0) {
            float bn = b2[n];
            cst(a.tmpv2 + b0 * Dm + n, pa + bn);
            cst(a.tmpv2 + (b0 + 1) * Dm + n, pb + bn);
          }
        }
      }
      gbar(a.slots, ++ep, bid, tid, lane, wave);
    }

    // --- S5: logits (8193 rows x 8 b/wave) with fused LN3(layer1) + running argmax ---
    {
      Frag xf[8];
#pragma unroll
      for (int j = 0; j < 8; ++j) {
        int b = g4 * 8 + j;
        Frag r = fadd(cfload(a.x2 + b * Dm, lane), cfload(a.tmpv2 + b * Dm, lane));
        xf[j] = fln(r, a.ln3_g + Dm, a.ln3_b + Dm, lane);
      }
      float* lg = a.outLogits + (size_t)i * Bn * V1;
      float pm[8]; int pidx[8];
#pragma unroll
      for (int j = 0; j < 8; ++j) { pm[j] = -1e30f; pidx[j] = 0; }
      for (int u = gw; u < V1 * 4; u += NGW) {
        int n = u >> 2;
        const float* wr = a.e2v_w + (size_t)n * Dm;
        float bn = a.e2v_b[n];
#pragma unroll
        for (int j = 0; j < 8; ++j) {
          float acc = fdot(wr, xf[j], lane);
          if (lane == 0) {
            float val = acc + bn;
            lg[(size_t)(g4 * 8 + j) * V1 + n] = val;   // host-read only: plain store
            if (val > pm[j]) { pm[j] = val; pidx[j] = n; }  // n ascending: first-max
          }
        }
      }
      if (lane == 0) {
#pragma unroll
        for (int j = 0; j < 8; ++j) cstp(a.partPack + (size_t)(gw * 8 + j) * 2, pm[j], pidx[j]);
      }
    }
    gbar(a.slots, ++ep, bid, tid, lane, wave);

    // --- S6: argmax combine over 1024 wave-partials (per-b block) + next embed ---
    if (bid < Bn) {
      const int b = bid;
      int w = (b >> 3) + tid * 4;          // waves with g4 == b>>3
      unsigned long long u = __hip_atomic_load(
          (const unsigned long long*)(a.partPack + (size_t)(w * 8 + (b & 7)) * 2),
          __ATOMIC_RELAXED, __HIP_MEMORY_SCOPE_AGENT);
      sv[tid] = __uint_as_float((unsigned)u);
      si[tid] = (int)(unsigned)(u >> 32);
      __syncthreads();
      for (int off = 512; off > 0; off >>= 1) {
        if (tid < off) {
          float v2 = sv[tid + off]; int i2 = si[tid + off];
          if (v2 > sv[tid] || (v2 == sv[tid] && i2 < si[tid])) { sv[tid] = v2; si[tid] = i2; }
        }
        __syncthreads();
      }
      if (tid == 0) { a.outToks[i * Bn + b] = (float)si[0]; sTok = si[0]; }
      __syncthreads();
      if (i + 1 < Lq && tid < 256) {
        int tok = sTok, t2 = tid * 2;
        float e0 = a.v2e_w[(size_t)tok * Dm + t2]     + pe_val(t2, i + 1);
        float e1 = a.v2e_w[(size_t)tok * Dm + t2 + 1] + pe_val(t2 + 1, i + 1);
        cst2(a.x + b * Dm + t2, e0, e1);
      }
    }
    gbar(a.slots, ++ep, bid, tid, lane, wave);
  }
}

}  // namespace

extern "C" void kernel_launch(void* const* d_in, const int* in_sizes, int n_in,
                              void* d_out, int out_size, void* d_ws, size_t ws_size,
                              hipStream_t stream) {
  (void)in_sizes; (void)n_in; (void)out_size; (void)ws_size;

  float* out = (float*)d_out;
  char* wsb = (char*)d_ws;

  Args a;
  a.meanings  = (const int*)d_in[0];
  a.emb_table = (const float*)d_in[1];
  a.v2e_w     = (const float*)d_in[2];
  a.e2v_w     = (const float*)d_in[3];
  a.e2v_b     = (const float*)d_in[4];
  a.sa_qkv_w  = (const float*)d_in[5];
  a.sa_qkv_b  = (const float*)d_in[6];
  a.sa_out_w  = (const float*)d_in[7];
  a.sa_out_b  = (const float*)d_in[8];
  a.ca_qkv_w  = (const float*)d_in[9];
  a.ca_qkv_b  = (const float*)d_in[10];
  a.ca_out_w  = (const float*)d_in[11];
  a.ca_out_b  = (const float*)d_in[12];
  a.ffn_w1    = (const float*)d_in[13];
  a.ffn_b1    = (const float*)d_in[14];
  a.ffn_w2    = (const float*)d_in[15];
  a.ffn_b2    = (const float*)d_in[16];
  a.ln1_g     = (const float*)d_in[17];
  a.ln1_b     = (const float*)d_in[18];
  a.ln2_g     = (const float*)d_in[19];
  a.ln2_b     = (const float*)d_in[20];
  a.ln3_g     = (const float*)d_in[21];
  a.ln3_b     = (const float*)d_in[22];
  a.outToks   = out;
  a.outLogits = out + Lq * Bn;

  a.slots = (unsigned*)wsb;                 // 256 u32
  hipMemsetAsync(wsb, 0, 4096, stream);

  float* ws = (float*)(wsb + 4096);
  a.q       = ws;                    ws += Bn * Dm;
  a.x       = ws;                    ws += Bn * Dm;
  a.xln     = ws;                    ws += Bn * Dm;
  a.x2      = ws;                    ws += Bn * Dm;
  a.tmpv    = ws;                    ws += Bn * Dm;
  a.tmpv2   = ws;                    ws += Bn * Dm;
  a.catmp   = ws;                    ws += NL * Bn * Dm;
  a.caC     = ws;                    ws += NL * Bn * Dm;
  a.h1      = ws;                    ws += Bn * DFF;
  a.kc      = ws;                    ws += NL * Lq * Bn * Dm;
  a.vc      = ws;                    ws += NL * Lq * Bn * Dm;
  a.partPack = ws;                   ws += NGW * 8 * 2;

  void* kp[] = { (void*)&a };
  hipLaunchCooperativeKernel((const void*)mega, dim3(NB), dim3(NT), kp, 0, stream);
}